// Round 2
// baseline (313.344 us; speedup 1.0000x reference)
//
#include <hip/hip_runtime.h>
#include <cstdint>
#include <cstddef>

#define NTOK 8192      // B*S
#define SLEN 2048
#define DM   768
#define NH   12
#define DKH  64

typedef __attribute__((ext_vector_type(8))) short bf16x8;
typedef __attribute__((ext_vector_type(4))) float f32x4;

__device__ __forceinline__ float b2f(unsigned short u) {
  return __uint_as_float(((unsigned)u) << 16);
}
__device__ __forceinline__ unsigned short f2b(float f) {
  unsigned u = __float_as_uint(f);
  u += 0x7fffu + ((u >> 16) & 1u);   // RNE (no NaN inputs here)
  return (unsigned short)(u >> 16);
}

__device__ __forceinline__ void gld16(const void* g, void* l) {
  __builtin_amdgcn_global_load_lds(
      (const __attribute__((address_space(1))) void*)g,
      (__attribute__((address_space(3))) void*)l, 16, 0, 0);
}

// ---------------- fp32 -> bf16 cast ----------------
__global__ void cast_bf16_kernel(const float* __restrict__ in,
                                 unsigned short* __restrict__ out, int n8) {
  int i = blockIdx.x * blockDim.x + threadIdx.x;
  if (i >= n8) return;
  const float4* p = (const float4*)(in + (size_t)i * 8);
  float4 a = p[0], b = p[1];
  union { unsigned short h[8]; bf16x8 v; } u;
  u.h[0] = f2b(a.x); u.h[1] = f2b(a.y); u.h[2] = f2b(a.z); u.h[3] = f2b(a.w);
  u.h[4] = f2b(b.x); u.h[5] = f2b(b.y); u.h[6] = f2b(b.z); u.h[7] = f2b(b.w);
  *(bf16x8*)(out + (size_t)i * 8) = u.v;
}

// ---------------- RoPE (in-place on bf16 Q or K) ----------------
__global__ void rope_kernel(unsigned short* __restrict__ X,
                            const int* __restrict__ pos, int total) {
  int idx = blockIdx.x * blockDim.x + threadIdx.x;
  if (idx >= total) return;
  int row = idx / 96, ch = idx - row * 96;   // 96 = DM/8 chunks per token
  int s = row & (SLEN - 1);
  int col = ch * 8;
  int p0 = (col & 63) >> 1;                  // pair index base within head
  float ps = (float)pos[s];
  unsigned short* ptr = X + (size_t)row * DM + col;
  bf16x8 v = *(bf16x8*)ptr;
  float f[8];
#pragma unroll
  for (int i = 0; i < 8; ++i) f[i] = b2f(((unsigned short*)&v)[i]);
  union { unsigned short h[8]; bf16x8 v; } o;
#pragma unroll
  for (int i = 0; i < 4; ++i) {
    float p = (float)(p0 + i);
    float freq = exp2f(p * -0.4152410118609203f);  // 10000^(-p/32)
    float ang = ps * freq;
    float sn, cs;
    __sincosf(ang, &sn, &cs);
    float x1 = f[2 * i], x2 = f[2 * i + 1];
    o.h[2 * i]     = f2b(x1 * cs - x2 * sn);
    o.h[2 * i + 1] = f2b(x1 * sn + x2 * cs);
  }
  *(bf16x8*)ptr = o.v;
}

// ---------------- GEMM: C[M][N] = sum_k A[m][k] * B[n][k] ----------------
__device__ __forceinline__ void stv(float* p, float v) { *p = v; }
__device__ __forceinline__ void stv(unsigned short* p, float v) { *p = f2b(v); }

template <typename CT>
__global__ __launch_bounds__(256, 2) void gemm_bt_kernel(
    const unsigned short* __restrict__ A,
    const unsigned short* __restrict__ B0, const unsigned short* __restrict__ B1,
    const unsigned short* __restrict__ B2,
    CT* __restrict__ C0, CT* __restrict__ C1, CT* __restrict__ C2,
    int N, int K) {
  const unsigned short* Bp = (blockIdx.z == 0) ? B0 : (blockIdx.z == 1) ? B1 : B2;
  CT* Cp = (blockIdx.z == 0) ? C0 : (blockIdx.z == 1) ? C1 : C2;
  const int tid = threadIdx.x, wid = tid >> 6, lane = tid & 63;
  const int lrow = lane & 15, lk8 = (lane >> 4) << 3;
  const int m0 = blockIdx.y * 128, n0 = blockIdx.x * 128;
  const int wm = (wid >> 1) * 64, wn = (wid & 1) * 64;
  const int sr = lane >> 3, sc = (lane & 7) * 8;
  __shared__ unsigned short At[128 * 64];
  __shared__ unsigned short Bt[128 * 64];
  f32x4 acc[4][4] = {};
  for (int k0 = 0; k0 < K; k0 += 64) {
    __syncthreads();
#pragma unroll
    for (int i = 0; i < 4; ++i) {
      int r = (wid * 4 + i) * 8 + sr;
      int k = sc ^ ((r & 7) << 3);
      gld16(A  + (size_t)(m0 + r) * K + k0 + k, &At[(wid * 4 + i) * 512]);
      gld16(Bp + (size_t)(n0 + r) * K + k0 + k, &Bt[(wid * 4 + i) * 512]);
    }
    __syncthreads();
    bf16x8 af[2][4], bfr[2][4];
#pragma unroll
    for (int ks = 0; ks < 2; ++ks)
#pragma unroll
      for (int mi = 0; mi < 4; ++mi) {
        int ra = wm + mi * 16 + lrow;
        af[ks][mi]  = *(const bf16x8*)&At[ra * 64 + ((ks * 32 + lk8) ^ ((ra & 7) << 3))];
        int rb = wn + mi * 16 + lrow;
        bfr[ks][mi] = *(const bf16x8*)&Bt[rb * 64 + ((ks * 32 + lk8) ^ ((rb & 7) << 3))];
      }
#pragma unroll
    for (int ks = 0; ks < 2; ++ks)
#pragma unroll
      for (int mi = 0; mi < 4; ++mi)
#pragma unroll
        for (int ni = 0; ni < 4; ++ni)
          acc[mi][ni] = __builtin_amdgcn_mfma_f32_16x16x32_bf16(
              af[ks][mi], bfr[ks][ni], acc[mi][ni], 0, 0, 0);
  }
#pragma unroll
  for (int mi = 0; mi < 4; ++mi)
#pragma unroll
    for (int ni = 0; ni < 4; ++ni)
#pragma unroll
      for (int r = 0; r < 4; ++r) {
        int row = m0 + wm + mi * 16 + (lane >> 4) * 4 + r;
        int col = n0 + wn + ni * 16 + lrow;
        stv(Cp + (size_t)row * N + col, acc[mi][ni][r]);
      }
}

// ---------------- causal flash attention ----------------
// QBLK=128, KVBLK=64. grid (16, 48); qt = 15 - blockIdx.x (heavy first).
// 4 waves; wave w owns q rows [w*32, w*32+32) (2 x 16-row fragments).
// K/V double-buffered; K via swizzled global_load_lds, V reg-staged transposed.
// Prefetch tile kt+1 issued before computing kt (latency hidden by MFMA+softmax).
__global__ __launch_bounds__(256, 3) void attn_kernel(
    const unsigned short* __restrict__ Q, const unsigned short* __restrict__ Kg,
    const unsigned short* __restrict__ V, unsigned short* __restrict__ O) {
  const int qt = (int)(gridDim.x - 1) - (int)blockIdx.x;
  const int bh = blockIdx.y;
  const int b = bh / NH, h = bh - b * NH;
  const size_t base = ((size_t)b * SLEN) * DM + h * DKH;
  const int tid = threadIdx.x, wid = tid >> 6, lane = tid & 63;
  const int lrow = lane & 15, g = lane >> 4, lk8 = g * 8;

  __shared__ unsigned short Kt[2][64 * 64];   // swizzled [kr][d]
  __shared__ unsigned short Vt[2][64 * 64];   // swizzled transposed [d][kr]
  __shared__ unsigned short Pl[4][32 * 64];   // per-wave P, swizzled [qr][kv]

  // Q fragments (2 row-frags x 2 k-slices), pre-scaled by 1/sqrt(64)=0.125
  bf16x8 qf[2][2];
#pragma unroll
  for (int mi = 0; mi < 2; ++mi)
#pragma unroll
    for (int ks = 0; ks < 2; ++ks) {
      const int qrow = qt * 128 + wid * 32 + mi * 16 + lrow;
      union { unsigned short h[8]; bf16x8 v; } u;
      u.v = *(const bf16x8*)&Q[base + (size_t)qrow * DM + ks * 32 + lk8];
#pragma unroll
      for (int j = 0; j < 8; ++j) u.h[j] = f2b(b2f(u.h[j]) * 0.125f);
      qf[mi][ks] = u.v;
    }

  f32x4 oacc[2][4] = {};
  float m_run[2][4], l_run[2][4];
#pragma unroll
  for (int mi = 0; mi < 2; ++mi)
#pragma unroll
    for (int r = 0; r < 4; ++r) { m_run[mi][r] = -1e30f; l_run[mi][r] = 0.f; }

  bf16x8 vpre[2];
  const int sr8 = lane >> 3, sc8 = (lane & 7) * 8;

  auto stageK = [&](int kt, int buf) {
#pragma unroll
    for (int p = 0; p < 2; ++p) {
      int r = (wid * 2 + p) * 8 + sr8;
      int c = sc8 ^ ((r & 7) << 3);
      gld16(Kg + base + (size_t)(kt * 64 + r) * DM + c,
            &Kt[buf][(wid * 2 + p) * 512]);
    }
  };
  auto loadV = [&](int kt) {
#pragma unroll
    for (int j8 = 0; j8 < 2; ++j8)
      vpre[j8] = *(const bf16x8*)&V[base + (size_t)(kt * 64 + lane) * DM + wid * 16 + j8 * 8];
  };
  auto writeV = [&](int buf) {
#pragma unroll
    for (int j8 = 0; j8 < 2; ++j8) {
      int c0 = wid * 16 + j8 * 8;
#pragma unroll
      for (int jj = 0; jj < 8; ++jj)
        Vt[buf][(c0 + jj) * 64 + (lane ^ (jj << 3))] = ((unsigned short*)&vpre[j8])[jj];
    }
  };

  const int nkt = 2 * qt + 2;
  // prologue: stage tile 0
  stageK(0, 0);
  loadV(0);
  writeV(0);            // compiler waits vmcnt for vpre use
  __syncthreads();      // drains gld16's vmcnt + lgkm

  for (int kt = 0; kt < nkt; ++kt) {
    const int cur = kt & 1;
    const bool pref = (kt + 1 < nkt);
    if (pref) { stageK(kt + 1, cur ^ 1); loadV(kt + 1); }

    const bool active = !(kt == 2 * qt + 1 && wid < 2);
    if (active) {
      // S = Q K^T
      f32x4 sa[2][4] = {};
#pragma unroll
      for (int ks = 0; ks < 2; ++ks)
#pragma unroll
        for (int ni = 0; ni < 4; ++ni) {
          const int krow = ni * 16 + lrow;
          bf16x8 kf = *(const bf16x8*)&Kt[cur][krow * 64 + ((ks * 32 + lk8) ^ ((krow & 7) << 3))];
#pragma unroll
          for (int mi = 0; mi < 2; ++mi)
            sa[mi][ni] = __builtin_amdgcn_mfma_f32_16x16x32_bf16(
                qf[mi][ks], kf, sa[mi][ni], 0, 0, 0);
        }

      // online softmax (per-row state; rows distributed as C-layout)
      const bool need_mask = (kt * 64 + 64 > qt * 128 + wid * 32);
      const int koff = kt * 64 - qt * 128;
      float p[2][4][4], mx[2][4];
#pragma unroll
      for (int mi = 0; mi < 2; ++mi)
#pragma unroll
        for (int r = 0; r < 4; ++r) mx[mi][r] = -1e30f;
#pragma unroll
      for (int mi = 0; mi < 2; ++mi)
#pragma unroll
        for (int ni = 0; ni < 4; ++ni)
#pragma unroll
          for (int r = 0; r < 4; ++r) {
            float s = sa[mi][ni][r];
            if (need_mask &&
                (koff + ni * 16 + lrow > wid * 32 + mi * 16 + g * 4 + r))
              s = -1e30f;
            p[mi][ni][r] = s;
            mx[mi][r] = fmaxf(mx[mi][r], s);
          }
#pragma unroll
      for (int mi = 0; mi < 2; ++mi)
#pragma unroll
        for (int r = 0; r < 4; ++r)
#pragma unroll
          for (int off = 1; off < 16; off <<= 1)
            mx[mi][r] = fmaxf(mx[mi][r], __shfl_xor(mx[mi][r], off));
#pragma unroll
      for (int mi = 0; mi < 2; ++mi)
#pragma unroll
        for (int r = 0; r < 4; ++r) {
          float mn = fmaxf(m_run[mi][r], mx[mi][r]);
          float scl = __expf(m_run[mi][r] - mn);
          m_run[mi][r] = mn;
          l_run[mi][r] *= scl;
#pragma unroll
          for (int ni = 0; ni < 4; ++ni) oacc[mi][ni][r] *= scl;
          float sum = 0.f;
#pragma unroll
          for (int ni = 0; ni < 4; ++ni) {
            p[mi][ni][r] = __expf(p[mi][ni][r] - mn);
            sum += p[mi][ni][r];
          }
#pragma unroll
          for (int off = 1; off < 16; off <<= 1) sum += __shfl_xor(sum, off);
          l_run[mi][r] += sum;
        }

      // P (C-layout) -> wave-private LDS (A-layout source), bf16
#pragma unroll
      for (int mi = 0; mi < 2; ++mi)
#pragma unroll
        for (int ni = 0; ni < 4; ++ni)
#pragma unroll
          for (int r = 0; r < 4; ++r) {
            int qr = mi * 16 + g * 4 + r;
            int kv = ni * 16 + lrow;
            Pl[wid][qr * 64 + (kv ^ ((qr & 7) << 3))] = f2b(p[mi][ni][r]);
          }

      // O += P V
#pragma unroll
      for (int ks = 0; ks < 2; ++ks) {
        bf16x8 pf[2];
#pragma unroll
        for (int mi = 0; mi < 2; ++mi) {
          int pr = mi * 16 + lrow;
          pf[mi] = *(const bf16x8*)&Pl[wid][pr * 64 + ((ks * 32 + lk8) ^ ((pr & 7) << 3))];
        }
#pragma unroll
        for (int ni = 0; ni < 4; ++ni) {
          int d = ni * 16 + lrow;
          bf16x8 vf = *(const bf16x8*)&Vt[cur][d * 64 + ((ks * 32 + lk8) ^ ((d & 7) << 3))];
#pragma unroll
          for (int mi = 0; mi < 2; ++mi)
            oacc[mi][ni] = __builtin_amdgcn_mfma_f32_16x16x32_bf16(
                pf[mi], vf, oacc[mi][ni], 0, 0, 0);
        }
      }
    }

    if (pref) writeV(cur ^ 1);   // vpre use forces vmcnt wait; lands before barrier
    __syncthreads();             // drains vmcnt (K gld16) + lgkm (V ds_writes)
  }

#pragma unroll
  for (int mi = 0; mi < 2; ++mi)
#pragma unroll
    for (int ni = 0; ni < 4; ++ni)
#pragma unroll
      for (int r = 0; r < 4; ++r) {
        int srow = qt * 128 + wid * 32 + mi * 16 + g * 4 + r;
        O[base + (size_t)srow * DM + ni * 16 + lrow] =
            f2b(oacc[mi][ni][r] / l_run[mi][r]);
      }
}

// ---------------- launch ----------------
extern "C" void kernel_launch(void* const* d_in, const int* in_sizes, int n_in,
                              void* d_out, int out_size, void* d_ws, size_t ws_size,
                              hipStream_t stream) {
  const float* x  = (const float*)d_in[0];
  const float* Wq = (const float*)d_in[1];
  const float* Wk = (const float*)d_in[2];
  const float* Wv = (const float*)d_in[3];
  const float* Wo = (const float*)d_in[4];
  const int* pos  = (const int*)d_in[5];
  float* out = (float*)d_out;

  char* ws = (char*)d_ws;
  size_t off = 0;
  auto carve = [&](size_t bytes) -> void* {
    void* p = ws + off;
    off += (bytes + 255) & ~(size_t)255;
    return p;
  };
  unsigned short* xb  = (unsigned short*)carve((size_t)NTOK * DM * 2);
  unsigned short* wqb = (unsigned short*)carve((size_t)DM * DM * 2);
  unsigned short* wkb = (unsigned short*)carve((size_t)DM * DM * 2);
  unsigned short* wvb = (unsigned short*)carve((size_t)DM * DM * 2);
  unsigned short* wob = (unsigned short*)carve((size_t)DM * DM * 2);
  unsigned short* Qb  = (unsigned short*)carve((size_t)NTOK * DM * 2);
  unsigned short* Kb  = (unsigned short*)carve((size_t)NTOK * DM * 2);
  unsigned short* Vb  = (unsigned short*)carve((size_t)NTOK * DM * 2);
  unsigned short* Ab  = (unsigned short*)carve((size_t)NTOK * DM * 2);

  const int n8x = NTOK * DM / 8;   // 786432
  const int n8w = DM * DM / 8;     // 73728
  cast_bf16_kernel<<<dim3((n8x + 255) / 256), dim3(256), 0, stream>>>(x, xb, n8x);
  cast_bf16_kernel<<<dim3((n8w + 255) / 256), dim3(256), 0, stream>>>(Wq, wqb, n8w);
  cast_bf16_kernel<<<dim3((n8w + 255) / 256), dim3(256), 0, stream>>>(Wk, wkb, n8w);
  cast_bf16_kernel<<<dim3((n8w + 255) / 256), dim3(256), 0, stream>>>(Wv, wvb, n8w);
  cast_bf16_kernel<<<dim3((n8w + 255) / 256), dim3(256), 0, stream>>>(Wo, wob, n8w);

  gemm_bt_kernel<unsigned short><<<dim3(6, 64, 3), dim3(256), 0, stream>>>(
      xb, wqb, wkb, wvb, Qb, Kb, Vb, DM, DM);

  const int nrope = NTOK * (DM / 8);
  rope_kernel<<<dim3((nrope + 255) / 256), dim3(256), 0, stream>>>(Qb, pos, nrope);
  rope_kernel<<<dim3((nrope + 255) / 256), dim3(256), 0, stream>>>(Kb, pos, nrope);

  attn_kernel<<<dim3(SLEN / 128, 4 * NH), dim3(256), 0, stream>>>(Qb, Kb, Vb, Ab);

  gemm_bt_kernel<float><<<dim3(6, 64, 1), dim3(256), 0, stream>>>(
      Ab, wob, wob, wob, out, out, out, DM, DM);
}

// Round 3
// 237.229 us; speedup vs baseline: 1.3208x; 1.3208x over previous
//
#include <hip/hip_runtime.h>
#include <cstdint>
#include <cstddef>

#define NTOK 8192      // B*S
#define SLEN 2048
#define DM   768
#define NH   12
#define DKH  64

typedef __attribute__((ext_vector_type(8))) short bf16x8;
typedef __attribute__((ext_vector_type(4))) float f32x4;

__device__ __forceinline__ float b2f(unsigned short u) {
  return __uint_as_float(((unsigned)u) << 16);
}
__device__ __forceinline__ unsigned short f2b(float f) {
  unsigned u = __float_as_uint(f);
  u += 0x7fffu + ((u >> 16) & 1u);   // RNE (no NaN inputs here)
  return (unsigned short)(u >> 16);
}

__device__ __forceinline__ void gld16(const void* g, void* l) {
  __builtin_amdgcn_global_load_lds(
      (const __attribute__((address_space(1))) void*)g,
      (__attribute__((address_space(3))) void*)l, 16, 0, 0);
}

// ---------------- fp32 -> bf16 cast ----------------
__global__ void cast_bf16_kernel(const float* __restrict__ in,
                                 unsigned short* __restrict__ out, int n8) {
  int i = blockIdx.x * blockDim.x + threadIdx.x;
  if (i >= n8) return;
  const float4* p = (const float4*)(in + (size_t)i * 8);
  float4 a = p[0], b = p[1];
  union { unsigned short h[8]; bf16x8 v; } u;
  u.h[0] = f2b(a.x); u.h[1] = f2b(a.y); u.h[2] = f2b(a.z); u.h[3] = f2b(a.w);
  u.h[4] = f2b(b.x); u.h[5] = f2b(b.y); u.h[6] = f2b(b.z); u.h[7] = f2b(b.w);
  *(bf16x8*)(out + (size_t)i * 8) = u.v;
}

// ---------------- RoPE (in-place on bf16 Q or K) ----------------
__global__ void rope_kernel(unsigned short* __restrict__ X,
                            const int* __restrict__ pos, int total) {
  int idx = blockIdx.x * blockDim.x + threadIdx.x;
  if (idx >= total) return;
  int row = idx / 96, ch = idx - row * 96;   // 96 = DM/8 chunks per token
  int s = row & (SLEN - 1);
  int col = ch * 8;
  int p0 = (col & 63) >> 1;                  // pair index base within head
  float ps = (float)pos[s];
  unsigned short* ptr = X + (size_t)row * DM + col;
  bf16x8 v = *(bf16x8*)ptr;
  float f[8];
#pragma unroll
  for (int i = 0; i < 8; ++i) f[i] = b2f(((unsigned short*)&v)[i]);
  union { unsigned short h[8]; bf16x8 v; } o;
#pragma unroll
  for (int i = 0; i < 4; ++i) {
    float p = (float)(p0 + i);
    float freq = exp2f(p * -0.4152410118609203f);  // 10000^(-p/32)
    float ang = ps * freq;
    float sn, cs;
    __sincosf(ang, &sn, &cs);
    float x1 = f[2 * i], x2 = f[2 * i + 1];
    o.h[2 * i]     = f2b(x1 * cs - x2 * sn);
    o.h[2 * i + 1] = f2b(x1 * sn + x2 * cs);
  }
  *(bf16x8*)ptr = o.v;
}

// ---------------- GEMM: C[M][N] = sum_k A[m][k] * B[n][k] ----------------
__device__ __forceinline__ void stv(float* p, float v) { *p = v; }
__device__ __forceinline__ void stv(unsigned short* p, float v) { *p = f2b(v); }

template <typename CT>
__global__ __launch_bounds__(256, 2) void gemm_bt_kernel(
    const unsigned short* __restrict__ A,
    const unsigned short* __restrict__ B0, const unsigned short* __restrict__ B1,
    const unsigned short* __restrict__ B2,
    CT* __restrict__ C0, CT* __restrict__ C1, CT* __restrict__ C2,
    int N, int K) {
  const unsigned short* Bp = (blockIdx.z == 0) ? B0 : (blockIdx.z == 1) ? B1 : B2;
  CT* Cp = (blockIdx.z == 0) ? C0 : (blockIdx.z == 1) ? C1 : C2;
  const int tid = threadIdx.x, wid = tid >> 6, lane = tid & 63;
  const int lrow = lane & 15, lk8 = (lane >> 4) << 3;
  const int m0 = blockIdx.y * 128, n0 = blockIdx.x * 128;
  const int wm = (wid >> 1) * 64, wn = (wid & 1) * 64;
  const int sr = lane >> 3, sc = (lane & 7) * 8;
  __shared__ unsigned short At[128 * 64];
  __shared__ unsigned short Bt[128 * 64];
  f32x4 acc[4][4] = {};
  for (int k0 = 0; k0 < K; k0 += 64) {
    __syncthreads();
#pragma unroll
    for (int i = 0; i < 4; ++i) {
      int r = (wid * 4 + i) * 8 + sr;
      int k = sc ^ ((r & 7) << 3);
      gld16(A  + (size_t)(m0 + r) * K + k0 + k, &At[(wid * 4 + i) * 512]);
      gld16(Bp + (size_t)(n0 + r) * K + k0 + k, &Bt[(wid * 4 + i) * 512]);
    }
    __syncthreads();
    bf16x8 af[2][4], bfr[2][4];
#pragma unroll
    for (int ks = 0; ks < 2; ++ks)
#pragma unroll
      for (int mi = 0; mi < 4; ++mi) {
        int ra = wm + mi * 16 + lrow;
        af[ks][mi]  = *(const bf16x8*)&At[ra * 64 + ((ks * 32 + lk8) ^ ((ra & 7) << 3))];
        int rb = wn + mi * 16 + lrow;
        bfr[ks][mi] = *(const bf16x8*)&Bt[rb * 64 + ((ks * 32 + lk8) ^ ((rb & 7) << 3))];
      }
#pragma unroll
    for (int ks = 0; ks < 2; ++ks)
#pragma unroll
      for (int mi = 0; mi < 4; ++mi)
#pragma unroll
        for (int ni = 0; ni < 4; ++ni)
          acc[mi][ni] = __builtin_amdgcn_mfma_f32_16x16x32_bf16(
              af[ks][mi], bfr[ks][ni], acc[mi][ni], 0, 0, 0);
  }
#pragma unroll
  for (int mi = 0; mi < 4; ++mi)
#pragma unroll
    for (int ni = 0; ni < 4; ++ni)
#pragma unroll
      for (int r = 0; r < 4; ++r) {
        int row = m0 + wm + mi * 16 + (lane >> 4) * 4 + r;
        int col = n0 + wn + ni * 16 + lrow;
        stv(Cp + (size_t)row * N + col, acc[mi][ni][r]);
      }
}

// ---------------- causal flash attention (swapped QK^T, lane-local softmax) ----
// QBLK=128, KVBLK=64. grid (16, 48); qt = 15 - blockIdx.x (heavy first).
// 4 waves; wave w owns q rows [w*32, w*32+32). S^T = mfma(K, Q): lane holds
// S[q = mi*16 + (lane&15)][k = ni*16 + g*4 + r] -> softmax state is per-lane
// scalar; P needs NO cross-lane redistribution for PV because we contract PV
// in a permuted virtual-k order and read V^T in that same order (2x ds_read_b64).
__global__ __launch_bounds__(256, 4) void attn_kernel(
    const unsigned short* __restrict__ Q, const unsigned short* __restrict__ Kg,
    const unsigned short* __restrict__ V, unsigned short* __restrict__ O) {
  const int qt = (int)(gridDim.x - 1) - (int)blockIdx.x;
  const int bh = blockIdx.y;
  const int b = bh / NH, h = bh - b * NH;
  const size_t base = ((size_t)b * SLEN) * DM + h * DKH;
  const int tid = threadIdx.x, wid = tid >> 6, lane = tid & 63;
  const int lrow = lane & 15, g = lane >> 4, lk8 = g * 8;

  __shared__ unsigned short Kt[2][64 * 64];   // swizzled [kr][d]
  __shared__ unsigned short Vt[2][64 * 64];   // swizzled transposed [d][kr]

  // Q fragments (B operand of swapped QK^T), pre-scaled by 1/sqrt(64)=0.125
  bf16x8 qf[2][2];
#pragma unroll
  for (int mi = 0; mi < 2; ++mi)
#pragma unroll
    for (int ks = 0; ks < 2; ++ks) {
      const int qrow = qt * 128 + wid * 32 + mi * 16 + lrow;
      union { unsigned short h[8]; bf16x8 v; } u;
      u.v = *(const bf16x8*)&Q[base + (size_t)qrow * DM + ks * 32 + lk8];
#pragma unroll
      for (int j = 0; j < 8; ++j) u.h[j] = f2b(b2f(u.h[j]) * 0.125f);
      qf[mi][ks] = u.v;
    }

  // O^T accumulators: oacc[mi][ni][r] = O[q=mi*16+lrow][d=ni*16+g*4+r]
  f32x4 oacc[2][4] = {};
  float m_run[2] = {-1e30f, -1e30f}, l_run[2] = {0.f, 0.f};
  const int qg0 = qt * 128 + wid * 32 + lrow;   // global q for mi=0 (mi=1: +16)

  bf16x8 vpre[2];
  const int sr8 = lane >> 3, sc8 = (lane & 7) * 8;

  auto stageK = [&](int kt, int buf) {
#pragma unroll
    for (int p = 0; p < 2; ++p) {
      int r = (wid * 2 + p) * 8 + sr8;
      int c = sc8 ^ ((r & 7) << 3);
      gld16(Kg + base + (size_t)(kt * 64 + r) * DM + c,
            &Kt[buf][(wid * 2 + p) * 512]);
    }
  };
  auto loadV = [&](int kt) {
#pragma unroll
    for (int j8 = 0; j8 < 2; ++j8)
      vpre[j8] = *(const bf16x8*)&V[base + (size_t)(kt * 64 + lane) * DM + wid * 16 + j8 * 8];
  };
  auto writeV = [&](int buf) {
#pragma unroll
    for (int j8 = 0; j8 < 2; ++j8) {
      int c0 = wid * 16 + j8 * 8;
#pragma unroll
      for (int jj = 0; jj < 8; ++jj)
        Vt[buf][(c0 + jj) * 64 + (lane ^ (jj << 3))] = ((unsigned short*)&vpre[j8])[jj];
    }
  };

  const int nkt = 2 * qt + 2;
  stageK(0, 0);
  loadV(0);
  writeV(0);
  __syncthreads();

  for (int kt = 0; kt < nkt; ++kt) {
    const int cur = kt & 1;
    const bool pref = (kt + 1 < nkt);
    if (pref) { stageK(kt + 1, cur ^ 1); loadV(kt + 1); }

    const bool active = !(kt == 2 * qt + 1 && wid < 2);
    if (active) {
      // S^T = K Q^T : sa[mi][ni][r] = S[q=mi*16+lrow][k=ni*16+g*4+r]
      f32x4 sa[2][4] = {};
#pragma unroll
      for (int ks = 0; ks < 2; ++ks)
#pragma unroll
        for (int ni = 0; ni < 4; ++ni) {
          const int krow = ni * 16 + lrow;
          bf16x8 kf = *(const bf16x8*)&Kt[cur][krow * 64 + ((ks * 32 + lk8) ^ ((krow & 7) << 3))];
#pragma unroll
          for (int mi = 0; mi < 2; ++mi)
            sa[mi][ni] = __builtin_amdgcn_mfma_f32_16x16x32_bf16(
                kf, qf[mi][ks], sa[mi][ni], 0, 0, 0);
        }

      const bool need_mask = (kt * 64 + 64 > qt * 128 + wid * 32);
      const int kbase = kt * 64 + g * 4;
      float p[2][4][4];
#pragma unroll
      for (int mi = 0; mi < 2; ++mi) {
        const int qg = qg0 + mi * 16;
        // mask + in-register row max (16 values) + 2 shfls
        float mx = -1e30f;
#pragma unroll
        for (int ni = 0; ni < 4; ++ni)
#pragma unroll
          for (int r = 0; r < 4; ++r) {
            float s = sa[mi][ni][r];
            if (need_mask && (kbase + ni * 16 + r > qg)) s = -1e30f;
            p[mi][ni][r] = s;
            mx = fmaxf(mx, s);
          }
        mx = fmaxf(mx, __shfl_xor(mx, 16));
        mx = fmaxf(mx, __shfl_xor(mx, 32));
        float mn = fmaxf(m_run[mi], mx);
        float scl = __expf(m_run[mi] - mn);
        m_run[mi] = mn;
        l_run[mi] *= scl;
#pragma unroll
        for (int ni = 0; ni < 4; ++ni) oacc[mi][ni] *= scl;
        float sum = 0.f;
#pragma unroll
        for (int ni = 0; ni < 4; ++ni)
#pragma unroll
          for (int r = 0; r < 4; ++r) {
            float e = __expf(p[mi][ni][r] - mn);
            p[mi][ni][r] = e;
            sum += e;
          }
        sum += __shfl_xor(sum, 16);
        sum += __shfl_xor(sum, 32);
        l_run[mi] += sum;
      }

      // pack P (lane-local!): pf[mi][ks] elem j: j<4 -> p[mi][2ks][j], else p[mi][2ks+1][j-4]
      bf16x8 pf[2][2];
#pragma unroll
      for (int mi = 0; mi < 2; ++mi)
#pragma unroll
        for (int ks = 0; ks < 2; ++ks) {
          union { unsigned short h[8]; bf16x8 v; } u;
#pragma unroll
          for (int j = 0; j < 4; ++j) {
            u.h[j]     = f2b(p[mi][2 * ks][j]);
            u.h[4 + j] = f2b(p[mi][2 * ks + 1][j]);
          }
          pf[mi][ks] = u.v;
        }

      // O^T += V^T P^T in permuted virtual-k order:
      // virtual kv = ks*32 + g*8 + j  <->  real k = 32ks + 16*(j>>2) + 4g + (j&3)
      const unsigned short* Vb_ = Vt[cur];
#pragma unroll
      for (int ks = 0; ks < 2; ++ks)
#pragma unroll
        for (int ni = 0; ni < 4; ++ni) {
          const int d = ni * 16 + lrow;
          const int ro = d * 64, xr = (d & 7) << 3;
          union { ushort4 q[2]; bf16x8 v; } uv;
          uv.q[0] = *(const ushort4*)&Vb_[ro + ((ks * 32 + g * 4) ^ xr)];
          uv.q[1] = *(const ushort4*)&Vb_[ro + ((ks * 32 + 16 + g * 4) ^ xr)];
#pragma unroll
          for (int mi = 0; mi < 2; ++mi)
            oacc[mi][ni] = __builtin_amdgcn_mfma_f32_16x16x32_bf16(
                uv.v, pf[mi][ks], oacc[mi][ni], 0, 0, 0);
        }
    }

    if (pref) writeV(cur ^ 1);
    __syncthreads();
  }

  // epilogue: lane holds O[q=qrow][d=ni*16+g*4+r]; pack 4 bf16 -> 8B store
#pragma unroll
  for (int mi = 0; mi < 2; ++mi) {
    const int qrow = qt * 128 + wid * 32 + mi * 16 + lrow;
    const float inv = 1.f / l_run[mi];
#pragma unroll
    for (int ni = 0; ni < 4; ++ni) {
      union { unsigned short h[4]; ushort4 u; } o;
#pragma unroll
      for (int r = 0; r < 4; ++r) o.h[r] = f2b(oacc[mi][ni][r] * inv);
      *(ushort4*)&O[base + (size_t)qrow * DM + ni * 16 + g * 4] = o.u;
    }
  }
}

// ---------------- launch ----------------
extern "C" void kernel_launch(void* const* d_in, const int* in_sizes, int n_in,
                              void* d_out, int out_size, void* d_ws, size_t ws_size,
                              hipStream_t stream) {
  const float* x  = (const float*)d_in[0];
  const float* Wq = (const float*)d_in[1];
  const float* Wk = (const float*)d_in[2];
  const float* Wv = (const float*)d_in[3];
  const float* Wo = (const float*)d_in[4];
  const int* pos  = (const int*)d_in[5];
  float* out = (float*)d_out;

  char* ws = (char*)d_ws;
  size_t off = 0;
  auto carve = [&](size_t bytes) -> void* {
    void* p = ws + off;
    off += (bytes + 255) & ~(size_t)255;
    return p;
  };
  unsigned short* xb  = (unsigned short*)carve((size_t)NTOK * DM * 2);
  unsigned short* wqb = (unsigned short*)carve((size_t)DM * DM * 2);
  unsigned short* wkb = (unsigned short*)carve((size_t)DM * DM * 2);
  unsigned short* wvb = (unsigned short*)carve((size_t)DM * DM * 2);
  unsigned short* wob = (unsigned short*)carve((size_t)DM * DM * 2);
  unsigned short* Qb  = (unsigned short*)carve((size_t)NTOK * DM * 2);
  unsigned short* Kb  = (unsigned short*)carve((size_t)NTOK * DM * 2);
  unsigned short* Vb  = (unsigned short*)carve((size_t)NTOK * DM * 2);
  unsigned short* Ab  = (unsigned short*)carve((size_t)NTOK * DM * 2);

  const int n8x = NTOK * DM / 8;   // 786432
  const int n8w = DM * DM / 8;     // 73728
  cast_bf16_kernel<<<dim3((n8x + 255) / 256), dim3(256), 0, stream>>>(x, xb, n8x);
  cast_bf16_kernel<<<dim3((n8w + 255) / 256), dim3(256), 0, stream>>>(Wq, wqb, n8w);
  cast_bf16_kernel<<<dim3((n8w + 255) / 256), dim3(256), 0, stream>>>(Wk, wkb, n8w);
  cast_bf16_kernel<<<dim3((n8w + 255) / 256), dim3(256), 0, stream>>>(Wv, wvb, n8w);
  cast_bf16_kernel<<<dim3((n8w + 255) / 256), dim3(256), 0, stream>>>(Wo, wob, n8w);

  gemm_bt_kernel<unsigned short><<<dim3(6, 64, 3), dim3(256), 0, stream>>>(
      xb, wqb, wkb, wvb, Qb, Kb, Vb, DM, DM);

  const int nrope = NTOK * (DM / 8);
  rope_kernel<<<dim3((nrope + 255) / 256), dim3(256), 0, stream>>>(Qb, pos, nrope);
  rope_kernel<<<dim3((nrope + 255) / 256), dim3(256), 0, stream>>>(Kb, pos, nrope);

  attn_kernel<<<dim3(SLEN / 128, 4 * NH), dim3(256), 0, stream>>>(Qb, Kb, Vb, Ab);

  gemm_bt_kernel<float><<<dim3(6, 64, 1), dim3(256), 0, stream>>>(
      Ab, wob, wob, wob, out, out, out, DM, DM);
}

// Round 4
// 206.118 us; speedup vs baseline: 1.5202x; 1.1509x over previous
//
#include <hip/hip_runtime.h>
#include <cstdint>
#include <cstddef>

#define NTOK 8192      // B*S
#define SLEN 2048
#define DM   768
#define NH   12
#define DKH  64

typedef __attribute__((ext_vector_type(8))) short bf16x8;
typedef __attribute__((ext_vector_type(4))) float f32x4;

__device__ __forceinline__ float b2f(unsigned short u) {
  return __uint_as_float(((unsigned)u) << 16);
}
__device__ __forceinline__ unsigned short f2b(float f) {
  unsigned u = __float_as_uint(f);
  u += 0x7fffu + ((u >> 16) & 1u);   // RNE (no NaN inputs here)
  return (unsigned short)(u >> 16);
}

__device__ __forceinline__ void gld16(const void* g, void* l) {
  __builtin_amdgcn_global_load_lds(
      (const __attribute__((address_space(1))) void*)g,
      (__attribute__((address_space(3))) void*)l, 16, 0, 0);
}

// counted-vmcnt barrier: allow the 4 newest VMEM ops (next-tile prefetch:
// 2 K gld16 + 2 V reg-loads) to stay in flight across the barrier.
#define BAR_V4() do {                                            \
    asm volatile("s_waitcnt vmcnt(4) lgkmcnt(0)" ::: "memory");  \
    __builtin_amdgcn_s_barrier();                                \
    __builtin_amdgcn_sched_barrier(0);                           \
  } while (0)

// ---------------- fp32 -> bf16 cast ----------------
__global__ void cast_bf16_kernel(const float* __restrict__ in,
                                 unsigned short* __restrict__ out, int n8) {
  int i = blockIdx.x * blockDim.x + threadIdx.x;
  if (i >= n8) return;
  const float4* p = (const float4*)(in + (size_t)i * 8);
  float4 a = p[0], b = p[1];
  union { unsigned short h[8]; bf16x8 v; } u;
  u.h[0] = f2b(a.x); u.h[1] = f2b(a.y); u.h[2] = f2b(a.z); u.h[3] = f2b(a.w);
  u.h[4] = f2b(b.x); u.h[5] = f2b(b.y); u.h[6] = f2b(b.z); u.h[7] = f2b(b.w);
  *(bf16x8*)(out + (size_t)i * 8) = u.v;
}

// ---------------- RoPE (in-place on bf16 Q or K) ----------------
__global__ void rope_kernel(unsigned short* __restrict__ X,
                            const int* __restrict__ pos, int total) {
  int idx = blockIdx.x * blockDim.x + threadIdx.x;
  if (idx >= total) return;
  int row = idx / 96, ch = idx - row * 96;   // 96 = DM/8 chunks per token
  int s = row & (SLEN - 1);
  int col = ch * 8;
  int p0 = (col & 63) >> 1;                  // pair index base within head
  float ps = (float)pos[s];
  unsigned short* ptr = X + (size_t)row * DM + col;
  bf16x8 v = *(bf16x8*)ptr;
  float f[8];
#pragma unroll
  for (int i = 0; i < 8; ++i) f[i] = b2f(((unsigned short*)&v)[i]);
  union { unsigned short h[8]; bf16x8 v; } o;
#pragma unroll
  for (int i = 0; i < 4; ++i) {
    float p = (float)(p0 + i);
    float freq = exp2f(p * -0.4152410118609203f);  // 10000^(-p/32)
    float ang = ps * freq;
    float sn, cs;
    __sincosf(ang, &sn, &cs);
    float x1 = f[2 * i], x2 = f[2 * i + 1];
    o.h[2 * i]     = f2b(x1 * cs - x2 * sn);
    o.h[2 * i + 1] = f2b(x1 * sn + x2 * cs);
  }
  *(bf16x8*)ptr = o.v;
}

// ---------------- GEMM: C[M][N] = sum_k A[m][k] * B[n][k] ----------------
__device__ __forceinline__ void stv(float* p, float v) { *p = v; }
__device__ __forceinline__ void stv(unsigned short* p, float v) { *p = f2b(v); }

template <typename CT>
__global__ __launch_bounds__(256, 2) void gemm_bt_kernel(
    const unsigned short* __restrict__ A,
    const unsigned short* __restrict__ B0, const unsigned short* __restrict__ B1,
    const unsigned short* __restrict__ B2,
    CT* __restrict__ C0, CT* __restrict__ C1, CT* __restrict__ C2,
    int N, int K) {
  const unsigned short* Bp = (blockIdx.z == 0) ? B0 : (blockIdx.z == 1) ? B1 : B2;
  CT* Cp = (blockIdx.z == 0) ? C0 : (blockIdx.z == 1) ? C1 : C2;
  const int tid = threadIdx.x, wid = tid >> 6, lane = tid & 63;
  const int lrow = lane & 15, lk8 = (lane >> 4) << 3;
  const int m0 = blockIdx.y * 128, n0 = blockIdx.x * 128;
  const int wm = (wid >> 1) * 64, wn = (wid & 1) * 64;
  const int sr = lane >> 3, sc = (lane & 7) * 8;
  __shared__ unsigned short At[128 * 64];
  __shared__ unsigned short Bt[128 * 64];
  f32x4 acc[4][4] = {};
  for (int k0 = 0; k0 < K; k0 += 64) {
    __syncthreads();
#pragma unroll
    for (int i = 0; i < 4; ++i) {
      int r = (wid * 4 + i) * 8 + sr;
      int k = sc ^ ((r & 7) << 3);
      gld16(A  + (size_t)(m0 + r) * K + k0 + k, &At[(wid * 4 + i) * 512]);
      gld16(Bp + (size_t)(n0 + r) * K + k0 + k, &Bt[(wid * 4 + i) * 512]);
    }
    __syncthreads();
    bf16x8 af[2][4], bfr[2][4];
#pragma unroll
    for (int ks = 0; ks < 2; ++ks)
#pragma unroll
      for (int mi = 0; mi < 4; ++mi) {
        int ra = wm + mi * 16 + lrow;
        af[ks][mi]  = *(const bf16x8*)&At[ra * 64 + ((ks * 32 + lk8) ^ ((ra & 7) << 3))];
        int rb = wn + mi * 16 + lrow;
        bfr[ks][mi] = *(const bf16x8*)&Bt[rb * 64 + ((ks * 32 + lk8) ^ ((rb & 7) << 3))];
      }
#pragma unroll
    for (int ks = 0; ks < 2; ++ks)
#pragma unroll
      for (int mi = 0; mi < 4; ++mi)
#pragma unroll
        for (int ni = 0; ni < 4; ++ni)
          acc[mi][ni] = __builtin_amdgcn_mfma_f32_16x16x32_bf16(
              af[ks][mi], bfr[ks][ni], acc[mi][ni], 0, 0, 0);
  }
#pragma unroll
  for (int mi = 0; mi < 4; ++mi)
#pragma unroll
    for (int ni = 0; ni < 4; ++ni)
#pragma unroll
      for (int r = 0; r < 4; ++r) {
        int row = m0 + wm + mi * 16 + (lane >> 4) * 4 + r;
        int col = n0 + wn + ni * 16 + lrow;
        stv(Cp + (size_t)row * N + col, acc[mi][ni][r]);
      }
}

// ---------------- causal flash attention ----------------
// Swapped QK^T (lane-local softmax), QBLK=128, KVBLK=64, grid (16,48) heavy-
// first. Distance-2 prefetch: K triple-buffered LDS via swizzled gld16, V in
// two named register sets (vA/vB) written transposed to padded LDS (72/row,
// conflict-free PV b64 reads). Counted-vmcnt barrier keeps next-tile loads in
// flight (no vmcnt(0) drain). Softmax in exp2 domain (log2e folded into Q).
__global__ __launch_bounds__(256, 3) void attn_kernel(
    const unsigned short* __restrict__ Q, const unsigned short* __restrict__ Kg,
    const unsigned short* __restrict__ V, unsigned short* __restrict__ O) {
  const int qt = (int)(gridDim.x - 1) - (int)blockIdx.x;
  const int bh = blockIdx.y;
  const int b = bh / NH, h = bh - b * NH;
  const size_t base = ((size_t)b * SLEN) * DM + h * DKH;
  const int tid = threadIdx.x, wid = tid >> 6, lane = tid & 63;
  const int lrow = lane & 15, g = lane >> 4, lk8 = g * 8;

  __shared__ unsigned short Kt[3][64 * 64];   // swizzled [kr][d], 3-deep
  __shared__ unsigned short Vt[2][64 * 72];   // transposed [d][kv], pad 72

  // Q fragments (B operand of swapped QK^T), scaled by 0.125*log2(e)
  bf16x8 qf[2][2];
#pragma unroll
  for (int mi = 0; mi < 2; ++mi)
#pragma unroll
    for (int ks = 0; ks < 2; ++ks) {
      const int qrow = qt * 128 + wid * 32 + mi * 16 + lrow;
      union { unsigned short h[8]; bf16x8 v; } u;
      u.v = *(const bf16x8*)&Q[base + (size_t)qrow * DM + ks * 32 + lk8];
#pragma unroll
      for (int j = 0; j < 8; ++j)
        u.h[j] = f2b(b2f(u.h[j]) * 0.18033688011112042f);
      qf[mi][ks] = u.v;
    }

  f32x4 oacc[2][4] = {};
  float m_run[2] = {-1e30f, -1e30f}, l_run[2] = {0.f, 0.f};
  const int qg0 = qt * 128 + wid * 32 + lrow;

  const int sr8 = lane >> 3, sc8 = (lane & 7) * 8;

  auto stageK = [&](int kt, int slot) {
#pragma unroll
    for (int p = 0; p < 2; ++p) {
      int r = (wid * 2 + p) * 8 + sr8;
      int c = sc8 ^ ((r & 7) << 3);
      gld16(Kg + base + (size_t)(kt * 64 + r) * DM + c,
            &Kt[slot][(wid * 2 + p) * 512]);
    }
  };
  auto loadV = [&](int kt, bf16x8& d0, bf16x8& d1) {
    const unsigned short* src = &V[base + (size_t)(kt * 64 + lane) * DM + wid * 16];
    d0 = *(const bf16x8*)src;
    d1 = *(const bf16x8*)(src + 8);
  };
  auto writeV = [&](const bf16x8& s0, const bf16x8& s1, int buf) {
#pragma unroll
    for (int jj = 0; jj < 8; ++jj) {
      Vt[buf][(wid * 16 + jj) * 72 + lane]     = ((const unsigned short*)&s0)[jj];
      Vt[buf][(wid * 16 + 8 + jj) * 72 + lane] = ((const unsigned short*)&s1)[jj];
    }
  };

  auto computeTile = [&](int kt, int slot, int vbuf) {
    const bool active = !(kt == 2 * qt + 1 && wid < 2);
    if (!active) return;
    // S^T = K Q^T : sa[mi][ni][r] = S[q=mi*16+lrow][k=ni*16+g*4+r] (log2 units)
    f32x4 sa[2][4] = {};
    const unsigned short* Ks = Kt[slot];
    __builtin_amdgcn_s_setprio(1);
#pragma unroll
    for (int ks = 0; ks < 2; ++ks)
#pragma unroll
      for (int ni = 0; ni < 4; ++ni) {
        const int krow = ni * 16 + lrow;
        bf16x8 kf = *(const bf16x8*)&Ks[krow * 64 + ((ks * 32 + lk8) ^ ((krow & 7) << 3))];
#pragma unroll
        for (int mi = 0; mi < 2; ++mi)
          sa[mi][ni] = __builtin_amdgcn_mfma_f32_16x16x32_bf16(
              kf, qf[mi][ks], sa[mi][ni], 0, 0, 0);
      }
    __builtin_amdgcn_s_setprio(0);

    const bool need_mask = (kt * 64 + 64 > qt * 128 + wid * 32);
    const int kbase = kt * 64 + g * 4;
    float p[2][4][4];
#pragma unroll
    for (int mi = 0; mi < 2; ++mi) {
      const int qg = qg0 + mi * 16;
      float mx = -1e30f;
#pragma unroll
      for (int ni = 0; ni < 4; ++ni)
#pragma unroll
        for (int r = 0; r < 4; ++r) {
          float s = sa[mi][ni][r];
          if (need_mask && (kbase + ni * 16 + r > qg)) s = -1e30f;
          p[mi][ni][r] = s;
          mx = fmaxf(mx, s);
        }
      mx = fmaxf(mx, __shfl_xor(mx, 16));
      mx = fmaxf(mx, __shfl_xor(mx, 32));
      float mn = fmaxf(m_run[mi], mx);
      float scl = exp2f(m_run[mi] - mn);
      m_run[mi] = mn;
      l_run[mi] *= scl;
#pragma unroll
      for (int ni = 0; ni < 4; ++ni) oacc[mi][ni] *= scl;
      float sum = 0.f;
#pragma unroll
      for (int ni = 0; ni < 4; ++ni)
#pragma unroll
        for (int r = 0; r < 4; ++r) {
          float e = exp2f(p[mi][ni][r] - mn);
          p[mi][ni][r] = e;
          sum += e;
        }
      sum += __shfl_xor(sum, 16);
      sum += __shfl_xor(sum, 32);
      l_run[mi] += sum;
    }

    // pack P (lane-local): virtual kv = ks*32 + g*8 + j <-> real k =
    // 32ks + 16*(j>>2) + 4g + (j&3)
    bf16x8 pf[2][2];
#pragma unroll
    for (int mi = 0; mi < 2; ++mi)
#pragma unroll
      for (int ks = 0; ks < 2; ++ks) {
        union { unsigned short h[8]; bf16x8 v; } u;
#pragma unroll
        for (int j = 0; j < 4; ++j) {
          u.h[j]     = f2b(p[mi][2 * ks][j]);
          u.h[4 + j] = f2b(p[mi][2 * ks + 1][j]);
        }
        pf[mi][ks] = u.v;
      }

    // O^T += V^T P^T in the same virtual-k order (padded rows: conflict-free)
    const unsigned short* Vb_ = Vt[vbuf];
    __builtin_amdgcn_s_setprio(1);
#pragma unroll
    for (int ks = 0; ks < 2; ++ks)
#pragma unroll
      for (int ni = 0; ni < 4; ++ni) {
        const int d = ni * 16 + lrow;
        const int ro = d * 72 + ks * 32 + g * 4;
        union { ushort4 q[2]; bf16x8 v; } uv;
        uv.q[0] = *(const ushort4*)&Vb_[ro];
        uv.q[1] = *(const ushort4*)&Vb_[ro + 16];
#pragma unroll
        for (int mi = 0; mi < 2; ++mi)
          oacc[mi][ni] = __builtin_amdgcn_mfma_f32_16x16x32_bf16(
              uv.v, pf[mi][ks], oacc[mi][ni], 0, 0, 0);
      }
    __builtin_amdgcn_s_setprio(0);
  };

  const int nkt = 2 * qt + 2;   // always even
  bf16x8 vA0, vA1, vB0, vB1;

  // prologue: tiles 0 and 1
  stageK(0, 0);
  loadV(0, vA0, vA1);
  stageK(1, 1);
  loadV(1, vB0, vB1);
  writeV(vA0, vA1, 0);          // compiler inserts precise vmcnt for vA
  BAR_V4();

  for (int kt2 = 0; kt2 < nkt; kt2 += 2) {
    // even iter kt2: K slot kt2%3, V buf 0; prefetch tile kt2+2 into vA
    if (kt2 + 2 < nkt) { stageK(kt2 + 2, (kt2 + 2) % 3); loadV(kt2 + 2, vA0, vA1); }
    computeTile(kt2, kt2 % 3, 0);
    if (kt2 + 1 < nkt) writeV(vB0, vB1, 1);
    BAR_V4();
    // odd iter kt2+1: K slot (kt2+1)%3, V buf 1; prefetch tile kt2+3 into vB
    if (kt2 + 3 < nkt) { stageK(kt2 + 3, (kt2 + 3) % 3); loadV(kt2 + 3, vB0, vB1); }
    computeTile(kt2 + 1, (kt2 + 1) % 3, 1);
    if (kt2 + 2 < nkt) writeV(vA0, vA1, 0);
    BAR_V4();
  }

  // epilogue
#pragma unroll
  for (int mi = 0; mi < 2; ++mi) {
    const int qrow = qt * 128 + wid * 32 + mi * 16 + lrow;
    const float inv = 1.f / l_run[mi];
#pragma unroll
    for (int ni = 0; ni < 4; ++ni) {
      union { unsigned short h[4]; ushort4 u; } o;
#pragma unroll
      for (int r = 0; r < 4; ++r) o.h[r] = f2b(oacc[mi][ni][r] * inv);
      *(ushort4*)&O[base + (size_t)qrow * DM + ni * 16 + g * 4] = o.u;
    }
  }
}

// ---------------- launch ----------------
extern "C" void kernel_launch(void* const* d_in, const int* in_sizes, int n_in,
                              void* d_out, int out_size, void* d_ws, size_t ws_size,
                              hipStream_t stream) {
  const float* x  = (const float*)d_in[0];
  const float* Wq = (const float*)d_in[1];
  const float* Wk = (const float*)d_in[2];
  const float* Wv = (const float*)d_in[3];
  const float* Wo = (const float*)d_in[4];
  const int* pos  = (const int*)d_in[5];
  float* out = (float*)d_out;

  char* ws = (char*)d_ws;
  size_t off = 0;
  auto carve = [&](size_t bytes) -> void* {
    void* p = ws + off;
    off += (bytes + 255) & ~(size_t)255;
    return p;
  };
  unsigned short* xb  = (unsigned short*)carve((size_t)NTOK * DM * 2);
  unsigned short* wqb = (unsigned short*)carve((size_t)DM * DM * 2);
  unsigned short* wkb = (unsigned short*)carve((size_t)DM * DM * 2);
  unsigned short* wvb = (unsigned short*)carve((size_t)DM * DM * 2);
  unsigned short* wob = (unsigned short*)carve((size_t)DM * DM * 2);
  unsigned short* Qb  = (unsigned short*)carve((size_t)NTOK * DM * 2);
  unsigned short* Kb  = (unsigned short*)carve((size_t)NTOK * DM * 2);
  unsigned short* Vb  = (unsigned short*)carve((size_t)NTOK * DM * 2);
  unsigned short* Ab  = (unsigned short*)carve((size_t)NTOK * DM * 2);

  const int n8x = NTOK * DM / 8;   // 786432
  const int n8w = DM * DM / 8;     // 73728
  cast_bf16_kernel<<<dim3((n8x + 255) / 256), dim3(256), 0, stream>>>(x, xb, n8x);
  cast_bf16_kernel<<<dim3((n8w + 255) / 256), dim3(256), 0, stream>>>(Wq, wqb, n8w);
  cast_bf16_kernel<<<dim3((n8w + 255) / 256), dim3(256), 0, stream>>>(Wk, wkb, n8w);
  cast_bf16_kernel<<<dim3((n8w + 255) / 256), dim3(256), 0, stream>>>(Wv, wvb, n8w);
  cast_bf16_kernel<<<dim3((n8w + 255) / 256), dim3(256), 0, stream>>>(Wo, wob, n8w);

  gemm_bt_kernel<unsigned short><<<dim3(6, 64, 3), dim3(256), 0, stream>>>(
      xb, wqb, wkb, wvb, Qb, Kb, Vb, DM, DM);

  const int nrope = NTOK * (DM / 8);
  rope_kernel<<<dim3((nrope + 255) / 256), dim3(256), 0, stream>>>(Qb, pos, nrope);
  rope_kernel<<<dim3((nrope + 255) / 256), dim3(256), 0, stream>>>(Kb, pos, nrope);

  attn_kernel<<<dim3(SLEN / 128, 4 * NH), dim3(256), 0, stream>>>(Qb, Kb, Vb, Ab);

  gemm_bt_kernel<float><<<dim3(6, 64, 1), dim3(256), 0, stream>>>(
      Ab, wob, wob, wob, out, out, out, DM, DM);
}

// Round 5
// 192.006 us; speedup vs baseline: 1.6320x; 1.0735x over previous
//
#include <hip/hip_runtime.h>
#include <cstdint>
#include <cstddef>

#define NTOK 8192      // B*S
#define SLEN 2048
#define DM   768
#define NH   12
#define DKH  64

typedef __attribute__((ext_vector_type(8))) short bf16x8;
typedef __attribute__((ext_vector_type(4))) float f32x4;

__device__ __forceinline__ float b2f(unsigned short u) {
  return __uint_as_float(((unsigned)u) << 16);
}
__device__ __forceinline__ unsigned short f2b(float f) {
  unsigned u = __float_as_uint(f);
  u += 0x7fffu + ((u >> 16) & 1u);   // RNE (no NaN inputs here)
  return (unsigned short)(u >> 16);
}

__device__ __forceinline__ void gld16(const void* g, void* l) {
  __builtin_amdgcn_global_load_lds(
      (const __attribute__((address_space(1))) void*)g,
      (__attribute__((address_space(3))) void*)l, 16, 0, 0);
}

// ---------------- fp32 -> bf16 cast ----------------
__global__ void cast_bf16_kernel(const float* __restrict__ in,
                                 unsigned short* __restrict__ out, int n8) {
  int i = blockIdx.x * blockDim.x + threadIdx.x;
  if (i >= n8) return;
  const float4* p = (const float4*)(in + (size_t)i * 8);
  float4 a = p[0], b = p[1];
  union { unsigned short h[8]; bf16x8 v; } u;
  u.h[0] = f2b(a.x); u.h[1] = f2b(a.y); u.h[2] = f2b(a.z); u.h[3] = f2b(a.w);
  u.h[4] = f2b(b.x); u.h[5] = f2b(b.y); u.h[6] = f2b(b.z); u.h[7] = f2b(b.w);
  *(bf16x8*)(out + (size_t)i * 8) = u.v;
}

// ---------------- RoPE (in-place on bf16 Q or K) ----------------
__global__ void rope_kernel(unsigned short* __restrict__ X,
                            const int* __restrict__ pos, int total) {
  int idx = blockIdx.x * blockDim.x + threadIdx.x;
  if (idx >= total) return;
  int row = idx / 96, ch = idx - row * 96;   // 96 = DM/8 chunks per token
  int s = row & (SLEN - 1);
  int col = ch * 8;
  int p0 = (col & 63) >> 1;                  // pair index base within head
  float ps = (float)pos[s];
  unsigned short* ptr = X + (size_t)row * DM + col;
  bf16x8 v = *(bf16x8*)ptr;
  float f[8];
#pragma unroll
  for (int i = 0; i < 8; ++i) f[i] = b2f(((unsigned short*)&v)[i]);
  union { unsigned short h[8]; bf16x8 v; } o;
#pragma unroll
  for (int i = 0; i < 4; ++i) {
    float p = (float)(p0 + i);
    float freq = exp2f(p * -0.4152410118609203f);  // 10000^(-p/32)
    float ang = ps * freq;
    float sn, cs;
    __sincosf(ang, &sn, &cs);
    float x1 = f[2 * i], x2 = f[2 * i + 1];
    o.h[2 * i]     = f2b(x1 * cs - x2 * sn);
    o.h[2 * i + 1] = f2b(x1 * sn + x2 * cs);
  }
  *(bf16x8*)ptr = o.v;
}

// ---------------- GEMM: C[M][N] = sum_k A[m][k] * B[n][k] ----------------
__device__ __forceinline__ void stv(float* p, float v) { *p = v; }
__device__ __forceinline__ void stv(unsigned short* p, float v) { *p = f2b(v); }

template <typename CT>
__global__ __launch_bounds__(256, 2) void gemm_bt_kernel(
    const unsigned short* __restrict__ A,
    const unsigned short* __restrict__ B0, const unsigned short* __restrict__ B1,
    const unsigned short* __restrict__ B2,
    CT* __restrict__ C0, CT* __restrict__ C1, CT* __restrict__ C2,
    int N, int K) {
  const unsigned short* Bp = (blockIdx.z == 0) ? B0 : (blockIdx.z == 1) ? B1 : B2;
  CT* Cp = (blockIdx.z == 0) ? C0 : (blockIdx.z == 1) ? C1 : C2;
  const int tid = threadIdx.x, wid = tid >> 6, lane = tid & 63;
  const int lrow = lane & 15, lk8 = (lane >> 4) << 3;
  const int m0 = blockIdx.y * 128, n0 = blockIdx.x * 128;
  const int wm = (wid >> 1) * 64, wn = (wid & 1) * 64;
  const int sr = lane >> 3, sc = (lane & 7) * 8;
  __shared__ unsigned short At[128 * 64];
  __shared__ unsigned short Bt[128 * 64];
  f32x4 acc[4][4] = {};
  for (int k0 = 0; k0 < K; k0 += 64) {
    __syncthreads();
#pragma unroll
    for (int i = 0; i < 4; ++i) {
      int r = (wid * 4 + i) * 8 + sr;
      int k = sc ^ ((r & 7) << 3);
      gld16(A  + (size_t)(m0 + r) * K + k0 + k, &At[(wid * 4 + i) * 512]);
      gld16(Bp + (size_t)(n0 + r) * K + k0 + k, &Bt[(wid * 4 + i) * 512]);
    }
    __syncthreads();
    bf16x8 af[2][4], bfr[2][4];
#pragma unroll
    for (int ks = 0; ks < 2; ++ks)
#pragma unroll
      for (int mi = 0; mi < 4; ++mi) {
        int ra = wm + mi * 16 + lrow;
        af[ks][mi]  = *(const bf16x8*)&At[ra * 64 + ((ks * 32 + lk8) ^ ((ra & 7) << 3))];
        int rb = wn + mi * 16 + lrow;
        bfr[ks][mi] = *(const bf16x8*)&Bt[rb * 64 + ((ks * 32 + lk8) ^ ((rb & 7) << 3))];
      }
#pragma unroll
    for (int ks = 0; ks < 2; ++ks)
#pragma unroll
      for (int mi = 0; mi < 4; ++mi)
#pragma unroll
        for (int ni = 0; ni < 4; ++ni)
          acc[mi][ni] = __builtin_amdgcn_mfma_f32_16x16x32_bf16(
              af[ks][mi], bfr[ks][ni], acc[mi][ni], 0, 0, 0);
  }
#pragma unroll
  for (int mi = 0; mi < 4; ++mi)
#pragma unroll
    for (int ni = 0; ni < 4; ++ni)
#pragma unroll
      for (int r = 0; r < 4; ++r) {
        int row = m0 + wm + mi * 16 + (lane >> 4) * 4 + r;
        int col = n0 + wn + ni * 16 + lrow;
        stv(Cp + (size_t)row * N + col, acc[mi][ni][r]);
      }
}

// ---------------- V transpose (per head) with PV virtual-k permutation -------
// VT[bh][d][S]: storage col S = tt*64 + s holds V[token = tt*64 + pi(s)][d]
// where pi(s) = (s&32) + 16*((s&7)>>2) + 4*((s>>3)&3) + (s&3). This makes each
// PV A-fragment a single contiguous 16B load in the attention kernel.
__global__ void transpose_v_kernel(const unsigned short* __restrict__ V,
                                   unsigned short* __restrict__ VT) {
  const int tt = blockIdx.x, bh = blockIdx.y;
  const int b = bh / NH, h = bh - b * NH;
  const unsigned short* src = V + ((size_t)b * SLEN + tt * 64) * DM + h * DKH;
  unsigned short* dst = VT + (size_t)bh * DKH * SLEN + tt * 64;
  __shared__ unsigned short lds[64][72];
  const int tid = threadIdx.x;
  const int r = tid >> 2, cq = tid & 3;
#pragma unroll
  for (int pass = 0; pass < 2; ++pass) {
    int c = cq * 8 + pass * 32;
    *(bf16x8*)&lds[r][c] = *(const bf16x8*)&src[(size_t)r * DM + c];
  }
  __syncthreads();
  const int d = tid >> 2;
#pragma unroll
  for (int pass = 0; pass < 2; ++pass) {
    int s0 = cq * 8 + pass * 32;
    union { unsigned short h[8]; bf16x8 v; } o;
#pragma unroll
    for (int j = 0; j < 8; ++j) {
      int pi = pass * 32 + 16 * (j >> 2) + 4 * cq + (j & 3);
      o.h[j] = lds[pi][d];
    }
    *(bf16x8*)&dst[(size_t)d * SLEN + s0] = o.v;
  }
}

// ---------------- causal flash attention: barrier-free, LDS-free -------------
// One independent wave (64 threads) per block; wave owns 32 q-rows.
// grid 3072 = 64 q-waves x 48 heads; blockIdx = (63-qw)*48 + bh so that
// blockIdx%8 == bh%8 pins each head to one XCD (6 heads ~3MB K+VT per 4MB L2)
// and heavy q-waves dispatch first. K frags loaded global->reg (16 rows x 64B,
// line-covering), V frags from pre-permuted VT (single 16B load each).
// Swapped QK^T => lane-local softmax (2 shfl per 32 rows). K dbuf 1 tile ahead.
__global__ __launch_bounds__(64, 2) void attn_kernel(
    const unsigned short* __restrict__ Q, const unsigned short* __restrict__ Kg,
    const unsigned short* __restrict__ VT, unsigned short* __restrict__ O) {
  const int i = blockIdx.x;
  const int qw = 63 - (i / 48);
  const int bh = i % 48;
  const int b = bh / NH, h = bh - b * NH;
  const size_t base = ((size_t)b * SLEN) * DM + h * DKH;
  const size_t vbase = (size_t)bh * DKH * SLEN;
  const int lane = threadIdx.x;
  const int lrow = lane & 15, g = lane >> 4;

  // Q fragments (B operand of swapped QK^T), scaled by 0.125*log2(e)
  bf16x8 qf[2][2];
#pragma unroll
  for (int mi = 0; mi < 2; ++mi)
#pragma unroll
    for (int ks = 0; ks < 2; ++ks) {
      const int qrow = qw * 32 + mi * 16 + lrow;
      union { unsigned short h[8]; bf16x8 v; } u;
      u.v = *(const bf16x8*)&Q[base + (size_t)qrow * DM + ks * 32 + g * 8];
#pragma unroll
      for (int j = 0; j < 8; ++j)
        u.h[j] = f2b(b2f(u.h[j]) * 0.18033688011112042f);
      qf[mi][ks] = u.v;
    }

  f32x4 oacc[2][4] = {};
  float m_run[2] = {-1e30f, -1e30f}, l_run[2] = {0.f, 0.f};
  const int qg0 = qw * 32 + lrow;
  const int nkt = (qw >> 1) + 1;

  bf16x8 kA[8], kB[8], vA[8];

  auto loadK = [&](int t, bf16x8* kf) {
#pragma unroll
    for (int ks = 0; ks < 2; ++ks)
#pragma unroll
      for (int ni = 0; ni < 4; ++ni)
        kf[ks * 4 + ni] = *(const bf16x8*)
            &Kg[base + (size_t)(t * 64 + ni * 16 + lrow) * DM + ks * 32 + g * 8];
  };
  auto loadV = [&](int t, bf16x8* vf) {
#pragma unroll
    for (int ks = 0; ks < 2; ++ks)
#pragma unroll
      for (int ni = 0; ni < 4; ++ni)
        vf[ks * 4 + ni] = *(const bf16x8*)
            &VT[vbase + (size_t)(ni * 16 + lrow) * SLEN + t * 64 + ks * 32 + g * 8];
  };

  auto compute = [&](int t, bf16x8* kf, bf16x8* vf) {
    // S^T = K Q^T : sa[mi][ni][r] = S[q=mi*16+lrow][k=t*64+ni*16+g*4+r] (log2)
    f32x4 sa[2][4] = {};
    __builtin_amdgcn_s_setprio(1);
#pragma unroll
    for (int ks = 0; ks < 2; ++ks)
#pragma unroll
      for (int ni = 0; ni < 4; ++ni)
#pragma unroll
        for (int mi = 0; mi < 2; ++mi)
          sa[mi][ni] = __builtin_amdgcn_mfma_f32_16x16x32_bf16(
              kf[ks * 4 + ni], qf[mi][ks], sa[mi][ni], 0, 0, 0);
    __builtin_amdgcn_s_setprio(0);

    const bool need_mask = (t * 64 + 64 > qw * 32);
    const int kb = t * 64 + g * 4;
#pragma unroll
    for (int mi = 0; mi < 2; ++mi) {
      const int qg = qg0 + mi * 16;
      float mx = -1e30f;
#pragma unroll
      for (int ni = 0; ni < 4; ++ni)
#pragma unroll
        for (int r = 0; r < 4; ++r) {
          float s = sa[mi][ni][r];
          if (need_mask && (kb + ni * 16 + r > qg)) s = -1e30f;
          sa[mi][ni][r] = s;
          mx = fmaxf(mx, s);
        }
      mx = fmaxf(mx, __shfl_xor(mx, 16));
      mx = fmaxf(mx, __shfl_xor(mx, 32));
      float mn = fmaxf(m_run[mi], mx);
      float scl = exp2f(m_run[mi] - mn);
      m_run[mi] = mn;
      l_run[mi] *= scl;
#pragma unroll
      for (int ni = 0; ni < 4; ++ni) oacc[mi][ni] *= scl;
      float sum = 0.f;
#pragma unroll
      for (int ni = 0; ni < 4; ++ni)
#pragma unroll
        for (int r = 0; r < 4; ++r) {
          float e = exp2f(sa[mi][ni][r] - mn);
          sa[mi][ni][r] = e;
          sum += e;
        }
      sum += __shfl_xor(sum, 16);
      sum += __shfl_xor(sum, 32);
      l_run[mi] += sum;
    }

    // pack P (lane-local): pf[mi][ks] elem j: j<4 -> sa[mi][2ks][j], else
    // sa[mi][2ks+1][j-4]  (virtual kv = ks*32+g*8+j <-> real k matches VT perm)
    bf16x8 pf[2][2];
#pragma unroll
    for (int mi = 0; mi < 2; ++mi)
#pragma unroll
      for (int ks = 0; ks < 2; ++ks) {
        union { unsigned short h[8]; bf16x8 v; } u;
#pragma unroll
        for (int j = 0; j < 4; ++j) {
          u.h[j]     = f2b(sa[mi][2 * ks][j]);
          u.h[4 + j] = f2b(sa[mi][2 * ks + 1][j]);
        }
        pf[mi][ks] = u.v;
      }

    // O^T += V^T P^T (A = VT frag, pre-permuted storage)
    __builtin_amdgcn_s_setprio(1);
#pragma unroll
    for (int ks = 0; ks < 2; ++ks)
#pragma unroll
      for (int ni = 0; ni < 4; ++ni)
#pragma unroll
        for (int mi = 0; mi < 2; ++mi)
          oacc[mi][ni] = __builtin_amdgcn_mfma_f32_16x16x32_bf16(
              vf[ks * 4 + ni], pf[mi][ks], oacc[mi][ni], 0, 0, 0);
    __builtin_amdgcn_s_setprio(0);
  };

  loadK(0, kA);
  for (int t = 0; t < nkt; t += 2) {
    loadV(t, vA);
    if (t + 1 < nkt) loadK(t + 1, kB);
    compute(t, kA, vA);
    if (t + 1 < nkt) {
      loadV(t + 1, vA);               // after PV of tile t (reg WAR dep)
      if (t + 2 < nkt) loadK(t + 2, kA);
      compute(t + 1, kB, vA);
    }
  }

  // epilogue: lane holds O[q=qrow][d=ni*16+g*4+r]
#pragma unroll
  for (int mi = 0; mi < 2; ++mi) {
    const int qrow = qw * 32 + mi * 16 + lrow;
    const float inv = 1.f / l_run[mi];
#pragma unroll
    for (int ni = 0; ni < 4; ++ni) {
      union { unsigned short h[4]; ushort4 u; } o;
#pragma unroll
      for (int r = 0; r < 4; ++r) o.h[r] = f2b(oacc[mi][ni][r] * inv);
      *(ushort4*)&O[base + (size_t)qrow * DM + ni * 16 + g * 4] = o.u;
    }
  }
}

// ---------------- launch ----------------
extern "C" void kernel_launch(void* const* d_in, const int* in_sizes, int n_in,
                              void* d_out, int out_size, void* d_ws, size_t ws_size,
                              hipStream_t stream) {
  const float* x  = (const float*)d_in[0];
  const float* Wq = (const float*)d_in[1];
  const float* Wk = (const float*)d_in[2];
  const float* Wv = (const float*)d_in[3];
  const float* Wo = (const float*)d_in[4];
  const int* pos  = (const int*)d_in[5];
  float* out = (float*)d_out;

  char* ws = (char*)d_ws;
  size_t off = 0;
  auto carve = [&](size_t bytes) -> void* {
    void* p = ws + off;
    off += (bytes + 255) & ~(size_t)255;
    return p;
  };
  unsigned short* xb  = (unsigned short*)carve((size_t)NTOK * DM * 2);
  unsigned short* wqb = (unsigned short*)carve((size_t)DM * DM * 2);
  unsigned short* wkb = (unsigned short*)carve((size_t)DM * DM * 2);
  unsigned short* wvb = (unsigned short*)carve((size_t)DM * DM * 2);
  unsigned short* wob = (unsigned short*)carve((size_t)DM * DM * 2);
  unsigned short* Qb  = (unsigned short*)carve((size_t)NTOK * DM * 2);
  unsigned short* Kb  = (unsigned short*)carve((size_t)NTOK * DM * 2);
  unsigned short* Vb  = (unsigned short*)carve((size_t)NTOK * DM * 2);
  unsigned short* Ab  = (unsigned short*)carve((size_t)NTOK * DM * 2);
  unsigned short* VTb = (unsigned short*)carve((size_t)4 * NH * DKH * SLEN * 2);

  const int n8x = NTOK * DM / 8;   // 786432
  const int n8w = DM * DM / 8;     // 73728
  cast_bf16_kernel<<<dim3((n8x + 255) / 256), dim3(256), 0, stream>>>(x, xb, n8x);
  cast_bf16_kernel<<<dim3((n8w + 255) / 256), dim3(256), 0, stream>>>(Wq, wqb, n8w);
  cast_bf16_kernel<<<dim3((n8w + 255) / 256), dim3(256), 0, stream>>>(Wk, wkb, n8w);
  cast_bf16_kernel<<<dim3((n8w + 255) / 256), dim3(256), 0, stream>>>(Wv, wvb, n8w);
  cast_bf16_kernel<<<dim3((n8w + 255) / 256), dim3(256), 0, stream>>>(Wo, wob, n8w);

  gemm_bt_kernel<unsigned short><<<dim3(6, 64, 3), dim3(256), 0, stream>>>(
      xb, wqb, wkb, wvb, Qb, Kb, Vb, DM, DM);

  const int nrope = NTOK * (DM / 8);
  rope_kernel<<<dim3((nrope + 255) / 256), dim3(256), 0, stream>>>(Qb, pos, nrope);
  rope_kernel<<<dim3((nrope + 255) / 256), dim3(256), 0, stream>>>(Kb, pos, nrope);

  transpose_v_kernel<<<dim3(SLEN / 64, 4 * NH), dim3(256), 0, stream>>>(Vb, VTb);

  attn_kernel<<<dim3(64 * 48), dim3(64), 0, stream>>>(Qb, Kb, VTb, Ab);

  gemm_bt_kernel<float><<<dim3(6, 64, 1), dim3(256), 0, stream>>>(
      Ab, wob, wob, wob, out, out, out, DM, DM);
}